// Round 1
// baseline (45.989 us; speedup 1.0000x reference)
//
#include <hip/hip_runtime.h>
#include <hip/hip_bf16.h>

// TrajectoryInformedSplatAttention: fused single-kernel implementation.
// B=4, S=4096, D=1024, maxd=8 (maxd = min(8, S-1) = 8, baked in).
//
// Per (b,s): traj[b,s,:] = sum_j comb_j * normed[b, s-8+j, :] / wsum
//   comb_j = lin(s,j) * tanh(2*mag[i]),  i = s-8+j  (valid when i >= 0)
//   normed[i] = (emb[i+1]-emb[i]) / mag[i]  (0 if mag <= 1e-6)
//   wsum = max(sum_j comb_j, 1e-8)
// Telescoped: traj = sum_{r=s-8..s} (c_{r-1} - c_r) * emb[r],
//   c_i = lin * q[i] / wsum,  q[i] = tanh(2*mag)/mag (or 0).

constexpr int B_ = 4;
constexpr int S_ = 4096;
constexpr int D_ = 1024;
constexpr int MAXD = 8;
constexpr int CHUNK = 16;   // s-values per block

__global__ __launch_bounds__(256)
void traj_splat_kernel(const float* __restrict__ emb, float* __restrict__ out) {
    const int s0 = blockIdx.x * CHUNK;
    const int b  = blockIdx.y;

    // diff rows needed: i in [max(0,s0-8), min(S-2, s0+CHUNK-2)]
    const int i_lo = max(0, s0 - MAXD);
    const int i_hi = min(S_ - 2, s0 + CHUNK - 2);
    const int n_diff = i_hi - i_lo + 1;          // <= CHUNK + 7

    __shared__ float smagw[CHUNK + MAXD];
    __shared__ float sq[CHUNK + MAXD];

    const int lane = threadIdx.x & 63;
    const int wave = threadIdx.x >> 6;           // 4 waves / block

    const float* __restrict__ embB = emb + (size_t)b * S_ * D_;

    // ---- Phase 1: per-diff-row magnitude -> scalars in LDS (wave per row) ----
    for (int li = wave; li < n_diff; li += 4) {
        const int i = i_lo + li;
        const float4* a4 = (const float4*)(embB + (size_t)i * D_) + lane * 4;
        const float4* c4 = (const float4*)(embB + (size_t)(i + 1) * D_) + lane * 4;
        float sum = 0.f;
        #pragma unroll
        for (int t = 0; t < 4; ++t) {
            const float4 av = a4[t];
            const float4 cv = c4[t];
            const float dx = cv.x - av.x, dy = cv.y - av.y;
            const float dz = cv.z - av.z, dw = cv.w - av.w;
            sum += dx * dx + dy * dy + dz * dz + dw * dw;
        }
        #pragma unroll
        for (int off = 32; off >= 1; off >>= 1)
            sum += __shfl_xor(sum, off, 64);
        if (lane == 0) {
            const float mag = sqrtf(sum);
            const float mw  = tanhf(2.f * mag);
            smagw[li] = mw;
            sq[li]    = (mag > 1e-6f) ? (mw / mag) : 0.f;
        }
    }
    __syncthreads();

    // ---- Phase 2: per-s stencil over 9 emb rows with rolling register window ----
    const int d0 = threadIdx.x * 4;              // 256 threads * float4 = 1024 floats

    float4 win[MAXD + 1];
    #pragma unroll
    for (int jr = 0; jr <= MAXD; ++jr) {
        const int r = s0 - MAXD + jr;
        if (r >= 0)
            win[jr] = *(const float4*)(embB + (size_t)r * D_ + d0);
        else
            win[jr] = make_float4(0.f, 0.f, 0.f, 0.f);
    }

    for (int sl = 0; sl < CHUNK; ++sl) {
        const int s  = s0 + sl;
        const int ws = min(MAXD, s);             // wsize
        const int lo = MAXD - ws;                // first valid j
        const float rden = 0.9f / (float)max(ws - 1, 1);

        float cpad[MAXD + 2];
        #pragma unroll
        for (int t = 0; t < MAXD + 2; ++t) cpad[t] = 0.f;

        float wsum = 0.f;
        #pragma unroll
        for (int j = 0; j < MAXD; ++j) {
            if (j >= lo) {
                const int li = s - MAXD + j - i_lo;   // index into LDS scalars
                const float lin = (ws > 1) ? (0.1f + rden * (float)(j - lo)) : 0.1f;
                wsum += lin * smagw[li];
                cpad[j + 1] = lin * sq[li];
            }
        }
        const float inv = 1.f / fmaxf(wsum, 1e-8f);

        float4 acc = make_float4(0.f, 0.f, 0.f, 0.f);
        #pragma unroll
        for (int jr = 0; jr <= MAXD; ++jr) {
            const float g = (cpad[jr] - cpad[jr + 1]) * inv;  // coef of emb row s-8+jr
            acc.x += g * win[jr].x;
            acc.y += g * win[jr].y;
            acc.z += g * win[jr].z;
            acc.w += g * win[jr].w;
        }
        *(float4*)(out + ((size_t)b * S_ + s) * D_ + d0) = acc;

        // shift window, load row s+1
        #pragma unroll
        for (int jr = 0; jr < MAXD; ++jr) win[jr] = win[jr + 1];
        if (sl + 1 < CHUNK) {
            const int r = s + 1;                 // <= s0 + CHUNK - 1 <= S-1
            win[MAXD] = *(const float4*)(embB + (size_t)r * D_ + d0);
        }
    }
}

extern "C" void kernel_launch(void* const* d_in, const int* in_sizes, int n_in,
                              void* d_out, int out_size, void* d_ws, size_t ws_size,
                              hipStream_t stream) {
    const float* emb = (const float*)d_in[0];
    float* out = (float*)d_out;

    dim3 grid(S_ / CHUNK, B_);   // 256 x 4 = 1024 blocks
    dim3 block(256);
    traj_splat_kernel<<<grid, block, 0, stream>>>(emb, out);
}

// Round 2
// 31.416 us; speedup vs baseline: 1.4639x; 1.4639x over previous
//
#include <hip/hip_runtime.h>
#include <hip/hip_bf16.h>

// TrajectoryInformedSplatAttention — register-resident single-pass version.
// B=4, S=4096, D=1024, maxd=8.
//
// Telescoped form: traj[b,s,:] = sum_{jr=0..8} g[s][jr] * emb[b, s-8+jr, :]
//   g[jr] = (c[jr-1] - c[jr]) / wsum,  c[j] = lin(s,j) * q[i],  i = s-8+j
//   q[i]  = tanh(2*mag_i)/mag_i (0 if mag<=1e-6),  wsum = max(sum lin*tanh(2*mag), 1e-8)
//
// Each block: 16 s-values, 256 threads (each owns one float4 of D).
// All 24 needed rows live in registers; magnitudes computed from the same
// registers via shuffle+LDS reduction; coefficients built once per s in LDS.

constexpr int B_ = 4;
constexpr int S_ = 4096;
constexpr int D_ = 1024;
constexpr int MAXD  = 8;
constexpr int CHUNK = 16;
constexpr int ROWS  = CHUNK + MAXD;      // 24 rows in the register window
constexpr int NDIFF = ROWS - 1;          // 23 adjacent diffs

__global__ __launch_bounds__(256)
void traj_splat_kernel(const float* __restrict__ emb, float* __restrict__ out) {
    const int s0   = blockIdx.x * CHUNK;
    const int b    = blockIdx.y;
    const int lane = threadIdx.x & 63;
    const int wave = threadIdx.x >> 6;   // 4 waves
    const int d0   = threadIdx.x * 4;    // 256 threads * 4 floats = 1024 = D

    const float* __restrict__ embB = emb + (size_t)b * S_ * D_;

    __shared__ float part[NDIFF][4];     // per-wave partial sumsq
    __shared__ float smagw[NDIFF];       // tanh(2*mag)
    __shared__ float sq[NDIFF];          // tanh(2*mag)/mag (or 0)
    __shared__ float gco[CHUNK][MAXD + 1];

    // ---- Phase A: load the whole 24-row window (independent loads, ILP) ----
    float4 win[ROWS];
    #pragma unroll
    for (int r = 0; r < ROWS; ++r) {
        const int row = s0 - MAXD + r;   // max = s0+15 <= S-1
        if (row >= 0)
            win[r] = *(const float4*)(embB + (size_t)row * D_ + d0);
        else
            win[r] = make_float4(0.f, 0.f, 0.f, 0.f);
    }

    // ---- Phase B: 23 diff magnitudes from registers ----
    #pragma unroll
    for (int li = 0; li < NDIFF; ++li) {
        const float4 a = win[li], c = win[li + 1];
        const float dx = c.x - a.x, dy = c.y - a.y;
        const float dz = c.z - a.z, dw = c.w - a.w;
        float sum = dx * dx + dy * dy + dz * dz + dw * dw;
        #pragma unroll
        for (int off = 32; off >= 1; off >>= 1)
            sum += __shfl_xor(sum, off, 64);
        if (lane == 0) part[li][wave] = sum;
    }
    __syncthreads();

    if (threadIdx.x < NDIFF) {
        const int li = threadIdx.x;
        const float s2  = part[li][0] + part[li][1] + part[li][2] + part[li][3];
        const float mag = sqrtf(s2);
        const float mw  = tanhf(2.f * mag);
        smagw[li] = mw;
        sq[li]    = (mag > 1e-6f) ? (mw / mag) : 0.f;
    }
    __syncthreads();

    // ---- Phase C1: 16 threads build the 9 stencil coefficients per s ----
    if (threadIdx.x < CHUNK) {
        const int sl = threadIdx.x;
        const int s  = s0 + sl;
        const int ws = min(MAXD, s);
        const int lo = MAXD - ws;
        const float rden = 0.9f / (float)max(ws - 1, 1);

        float cpad[MAXD + 2];
        #pragma unroll
        for (int t = 0; t < MAXD + 2; ++t) cpad[t] = 0.f;

        float wsum = 0.f;
        #pragma unroll
        for (int j = 0; j < MAXD; ++j) {
            if (j >= lo) {
                const int li = sl + j;                 // diff index in window
                const float lin = (ws > 1) ? (0.1f + rden * (float)(j - lo)) : 0.1f;
                wsum += lin * smagw[li];
                cpad[j + 1] = lin * sq[li];
            }
        }
        const float inv = 1.f / fmaxf(wsum, 1e-8f);
        #pragma unroll
        for (int jr = 0; jr <= MAXD; ++jr)
            gco[sl][jr] = (cpad[jr] - cpad[jr + 1]) * inv;
    }
    __syncthreads();

    // ---- Phase C2: outputs from registers, scalar-broadcast coefficients ----
    #pragma unroll
    for (int sl = 0; sl < CHUNK; ++sl) {
        float4 acc = make_float4(0.f, 0.f, 0.f, 0.f);
        #pragma unroll
        for (int jr = 0; jr <= MAXD; ++jr) {
            const float g = gco[sl][jr];
            acc.x += g * win[sl + jr].x;
            acc.y += g * win[sl + jr].y;
            acc.z += g * win[sl + jr].z;
            acc.w += g * win[sl + jr].w;
        }
        *(float4*)(out + ((size_t)b * S_ + s0 + sl) * D_ + d0) = acc;
    }
}

extern "C" void kernel_launch(void* const* d_in, const int* in_sizes, int n_in,
                              void* d_out, int out_size, void* d_ws, size_t ws_size,
                              hipStream_t stream) {
    const float* emb = (const float*)d_in[0];
    float* out = (float*)d_out;

    dim3 grid(S_ / CHUNK, B_);   // 256 x 4 = 1024 blocks
    dim3 block(256);
    traj_splat_kernel<<<grid, block, 0, stream>>>(emb, out);
}

// Round 3
// 29.705 us; speedup vs baseline: 1.5482x; 1.0576x over previous
//
#include <hip/hip_runtime.h>
#include <hip/hip_bf16.h>

// TrajectoryInformedSplatAttention — register-resident, CHUNK=32, XCD-swizzled.
// B=4, S=4096, D=1024, maxd=8.
//
// traj[b,s,:] = sum_{jr=0..8} g[s][jr] * emb[b, s-8+jr, :]   (telescoped)
//   g[jr] = (c[jr-1]-c[jr])/wsum, c[j] = lin(s,j)*q[i], i=s-8+j
//   q = tanh(2*mag)/mag (0 if mag<=1e-6), wsum = max(sum lin*tanh(2*mag),1e-8)

constexpr int B_ = 4;
constexpr int S_ = 4096;
constexpr int D_ = 1024;
constexpr int MAXD  = 8;
constexpr int CHUNK = 32;
constexpr int ROWS  = CHUNK + MAXD;      // 40 rows in the register window
constexpr int NDIFF = ROWS - 1;          // 39 adjacent diffs
constexpr int NCHUNK = S_ / CHUNK;       // 128 s-chunks per batch
constexpr int NWG    = NCHUNK * B_;      // 512 blocks
constexpr int NXCD   = 8;

__global__ __launch_bounds__(256, 2)
void traj_splat_kernel(const float* __restrict__ emb, float* __restrict__ out) {
    // XCD-aware swizzle: consecutive s-chunks land on the same XCD so the
    // 8-row halo between neighbor blocks is an L2 hit. NWG % 8 == 0 -> bijective.
    const int bid = blockIdx.x;
    const int lin = (bid % NXCD) * (NWG / NXCD) + bid / NXCD;
    const int schunk = lin & (NCHUNK - 1);
    const int b      = lin >> 7;          // lin / NCHUNK

    const int s0   = schunk * CHUNK;
    const int lane = threadIdx.x & 63;
    const int wave = threadIdx.x >> 6;    // 4 waves
    const int d0   = threadIdx.x * 4;     // 256 threads * 4 floats = 1024 = D

    const float* __restrict__ embB = emb + (size_t)b * S_ * D_;

    __shared__ float part[NDIFF][4][4];   // per-wave 4 partial sums
    __shared__ float smagw[NDIFF];        // tanh(2*mag)
    __shared__ float sq[NDIFF];           // tanh(2*mag)/mag (or 0)
    __shared__ float gco[CHUNK][12];      // 9 coefs padded to 12 (16B-aligned rows)

    // ---- Phase A: load the whole 40-row window (independent loads, ILP) ----
    float4 win[ROWS];
    #pragma unroll
    for (int r = 0; r < ROWS; ++r) {
        const int row = s0 - MAXD + r;    // max = s0+31 <= S-1
        if (row >= 0)
            win[r] = *(const float4*)(embB + (size_t)row * D_ + d0);
        else
            win[r] = make_float4(0.f, 0.f, 0.f, 0.f);
    }

    // ---- Phase B: 39 diff magnitudes; 4-level butterfly -> 4 partials/wave ----
    #pragma unroll
    for (int li = 0; li < NDIFF; ++li) {
        const float4 a = win[li], c = win[li + 1];
        const float dx = c.x - a.x, dy = c.y - a.y;
        const float dz = c.z - a.z, dw = c.w - a.w;
        float sum = dx * dx + dy * dy + dz * dz + dw * dw;
        sum += __shfl_xor(sum, 32, 64);
        sum += __shfl_xor(sum, 16, 64);
        sum += __shfl_xor(sum,  8, 64);
        sum += __shfl_xor(sum,  4, 64);
        if (lane < 4) part[li][wave][lane] = sum;   // lanes 0..3 hold group sums
    }
    __syncthreads();

    if (threadIdx.x < NDIFF) {
        const int li = threadIdx.x;
        float s2 = 0.f;
        #pragma unroll
        for (int w = 0; w < 4; ++w)
            #pragma unroll
            for (int k = 0; k < 4; ++k)
                s2 += part[li][w][k];
        const float mag = sqrtf(s2);
        const float mw  = tanhf(2.f * mag);
        smagw[li] = mw;
        sq[li]    = (mag > 1e-6f) ? (mw / mag) : 0.f;
    }
    __syncthreads();

    // ---- Phase C1: CHUNK threads build the 9 stencil coefficients per s ----
    if (threadIdx.x < CHUNK) {
        const int sl = threadIdx.x;
        const int s  = s0 + sl;
        const int ws = min(MAXD, s);
        const int lo = MAXD - ws;
        const float rden = 0.9f / (float)max(ws - 1, 1);

        float cpad[MAXD + 2];
        #pragma unroll
        for (int t = 0; t < MAXD + 2; ++t) cpad[t] = 0.f;

        float wsum = 0.f;
        #pragma unroll
        for (int j = 0; j < MAXD; ++j) {
            if (j >= lo) {
                const int li = sl + j;                 // diff index in window
                const float lin2 = (ws > 1) ? (0.1f + rden * (float)(j - lo)) : 0.1f;
                wsum += lin2 * smagw[li];
                cpad[j + 1] = lin2 * sq[li];
            }
        }
        const float inv = 1.f / fmaxf(wsum, 1e-8f);
        #pragma unroll
        for (int jr = 0; jr <= MAXD; ++jr)
            gco[sl][jr] = (cpad[jr] - cpad[jr + 1]) * inv;
    }
    __syncthreads();

    // ---- Phase C2: outputs from registers, packed coefficient reads ----
    float* outB = out + ((size_t)b * S_ + s0) * D_ + d0;
    #pragma unroll
    for (int sl = 0; sl < CHUNK; ++sl) {
        const float4 g0 = *(const float4*)&gco[sl][0];   // g[0..3]
        const float4 g1 = *(const float4*)&gco[sl][4];   // g[4..7]
        const float  g8 = gco[sl][8];

        float4 acc;
        acc.x = g0.x * win[sl].x; acc.y = g0.x * win[sl].y;
        acc.z = g0.x * win[sl].z; acc.w = g0.x * win[sl].w;
        const float gs[8] = {g0.y, g0.z, g0.w, g1.x, g1.y, g1.z, g1.w, g8};
        #pragma unroll
        for (int jr = 1; jr <= MAXD; ++jr) {
            const float g = gs[jr - 1];
            acc.x += g * win[sl + jr].x;
            acc.y += g * win[sl + jr].y;
            acc.z += g * win[sl + jr].z;
            acc.w += g * win[sl + jr].w;
        }
        *(float4*)(outB + (size_t)sl * D_) = acc;
    }
}

extern "C" void kernel_launch(void* const* d_in, const int* in_sizes, int n_in,
                              void* d_out, int out_size, void* d_ws, size_t ws_size,
                              hipStream_t stream) {
    const float* emb = (const float*)d_in[0];
    float* out = (float*)d_out;

    dim3 grid(NWG);      // 512 blocks, 1-D, swizzled in-kernel
    dim3 block(256);
    traj_splat_kernel<<<grid, block, 0, stream>>>(emb, out);
}